// Round 2
// baseline (71.297 us; speedup 1.0000x reference)
//
#include <hip/hip_runtime.h>

#define Hdim   128
#define Anodes 512
#define Bbatch 64
#define Eedges 16384
#define AMASK  (Anodes - 1)

// ws float offsets
#define WS_CNT 0
#define WS_C   512
#define WS_S   1024
#define WS_U   (1024 + 65536)
#define WS_TOTAL (1024 + 65536 + 65536)

__global__ void k_init(float* ws) {
    int i = blockIdx.x * blockDim.x + threadIdx.x;
    for (; i < WS_TOTAL; i += gridDim.x * blockDim.x) ws[i] = 0.f;
}

__global__ void k_cnt(const int* __restrict__ ei, float* __restrict__ ws) {
    int t = blockIdx.x * blockDim.x + threadIdx.x;
    if (t < Eedges) {
        int dst = ei[Eedges + t] & AMASK;
        atomicAdd(ws + WS_CNT + dst, 1.0f);
    }
}

// Block a: W[a,h] = wfc[a*H+h]/max(cnt,1);  S[a,k] = sum_h w2[k*H+h]*W[a,h]
// Also accumulates C = sum_{a:cnt>0} sum_h b2[h]*wfc[a*H+h]
__global__ void k_S(const float* __restrict__ w2, const float* __restrict__ wfc,
                    const float* __restrict__ b2, float* __restrict__ ws) {
    __shared__ float Wrow[Hdim];
    __shared__ float red[2];
    const int a = blockIdx.x;
    const int h = threadIdx.x;   // also used as k below
    const float c   = ws[WS_CNT + a];
    const float inv = 1.0f / fmaxf(c, 1.0f);
    const float wf  = wfc[a * Hdim + h];
    Wrow[h] = wf * inv;
    float cb = (c > 0.f) ? b2[h] * wf : 0.f;
    for (int off = 32; off; off >>= 1) cb += __shfl_down(cb, off, 64);
    if ((h & 63) == 0) red[h >> 6] = cb;
    __syncthreads();
    if (h == 0 && (red[0] + red[1]) != 0.f) atomicAdd(ws + WS_C, red[0] + red[1]);
    float s = 0.f;
    #pragma unroll 8
    for (int hh = 0; hh < Hdim; ++hh) s += w2[h * Hdim + hh] * Wrow[hh];
    ws[WS_S + a * Hdim + h] = s;
}

// U[src,:] += S[dst,:] over all edges
__global__ void k_U(const int* __restrict__ ei, float* __restrict__ ws) {
    int idx = blockIdx.x * blockDim.x + threadIdx.x;
    const int total = Eedges * Hdim;
    for (; idx < total; idx += gridDim.x * blockDim.x) {
        int e = idx >> 7, k = idx & (Hdim - 1);
        int src = ei[e] & AMASK, dst = ei[Eedges + e] & AMASK;
        atomicAdd(ws + WS_U + src * Hdim + k, ws[WS_S + dst * Hdim + k]);
    }
}

__global__ void k_outinit(const float* __restrict__ bfc, const float* __restrict__ ws,
                          float* __restrict__ out) {
    int t = threadIdx.x;
    if (t < Bbatch) out[t] = bfc[0] + ws[WS_C];
}

// out[b] += sum over 32 rows of relu(x_row @ w1 + b1) . U[a,:]
__global__ __launch_bounds__(256, 2)
void k_main(const float* __restrict__ x, const float* __restrict__ w1,
            const float* __restrict__ b1, const float* __restrict__ ws,
            float* __restrict__ out) {
    __shared__ float4 w1s[Hdim * 32];   // [h][kquad] : 64 KB
    __shared__ float4 xs[32 * 32];      // [r][hquad] : 16 KB
    __shared__ float red[4];

    const int tid  = threadIdx.x;
    const int row0 = blockIdx.x * 32;
    const int b    = row0 / Anodes;
    const int a0   = row0 % Anodes;

    const float4* w1v = (const float4*)w1;
    for (int i = tid; i < Hdim * 32; i += 256) w1s[i] = w1v[i];
    const float4* xv = (const float4*)(x + (size_t)row0 * Hdim);
    for (int i = tid; i < 32 * 32; i += 256) xs[i] = xv[i];
    __syncthreads();

    const int kt = tid & 31;    // col quad: k0 = kt*4
    const int rt = tid >> 5;    // row tile: r0 = rt*4
    const int r0 = rt * 4;

    float z[4][4];
    const float4 b1q = ((const float4*)b1)[kt];
    #pragma unroll
    for (int i = 0; i < 4; ++i) { z[i][0] = b1q.x; z[i][1] = b1q.y; z[i][2] = b1q.z; z[i][3] = b1q.w; }

    #pragma unroll 2
    for (int h = 0; h < Hdim; h += 4) {
        float4 wv0 = w1s[(h + 0) * 32 + kt];
        float4 wv1 = w1s[(h + 1) * 32 + kt];
        float4 wv2 = w1s[(h + 2) * 32 + kt];
        float4 wv3 = w1s[(h + 3) * 32 + kt];
        #pragma unroll
        for (int i = 0; i < 4; ++i) {
            float4 xr = xs[(r0 + i) * 32 + (h >> 2)];
            z[i][0] += xr.x * wv0.x + xr.y * wv1.x + xr.z * wv2.x + xr.w * wv3.x;
            z[i][1] += xr.x * wv0.y + xr.y * wv1.y + xr.z * wv2.y + xr.w * wv3.y;
            z[i][2] += xr.x * wv0.z + xr.y * wv1.z + xr.z * wv2.z + xr.w * wv3.z;
            z[i][3] += xr.x * wv0.w + xr.y * wv1.w + xr.z * wv2.w + xr.w * wv3.w;
        }
    }

    float acc = 0.f;
    const float4* Uv = (const float4*)(ws + WS_U);
    #pragma unroll
    for (int i = 0; i < 4; ++i) {
        float4 uq = Uv[(a0 + r0 + i) * 32 + kt];
        acc += fmaxf(z[i][0], 0.f) * uq.x + fmaxf(z[i][1], 0.f) * uq.y
             + fmaxf(z[i][2], 0.f) * uq.z + fmaxf(z[i][3], 0.f) * uq.w;
    }
    for (int off = 32; off; off >>= 1) acc += __shfl_down(acc, off, 64);
    if ((tid & 63) == 0) red[tid >> 6] = acc;
    __syncthreads();
    if (tid == 0) atomicAdd(out + b, red[0] + red[1] + red[2] + red[3]);
}

extern "C" void kernel_launch(void* const* d_in, const int* in_sizes, int n_in,
                              void* d_out, int out_size, void* d_ws, size_t ws_size,
                              hipStream_t stream) {
    const float* x   = (const float*)d_in[0];
    // d_in[1] = pos (unused by the reference computation)
    const int*   ei  = (const int*)d_in[2];       // int64 in reference -> int32 from harness
    const float* w1  = (const float*)d_in[3];
    const float* b1  = (const float*)d_in[4];
    const float* w2  = (const float*)d_in[5];
    const float* b2  = (const float*)d_in[6];
    const float* wfc = (const float*)d_in[7];
    const float* bfc = (const float*)d_in[8];
    float* out = (float*)d_out;
    float* ws  = (float*)d_ws;

    hipLaunchKernelGGL(k_init,    dim3(256),    dim3(256), 0, stream, ws);
    hipLaunchKernelGGL(k_cnt,     dim3(64),     dim3(256), 0, stream, ei, ws);
    hipLaunchKernelGGL(k_S,       dim3(Anodes), dim3(Hdim), 0, stream, w2, wfc, b2, ws);
    hipLaunchKernelGGL(k_U,       dim3(2048),   dim3(256), 0, stream, ei, ws);
    hipLaunchKernelGGL(k_outinit, dim3(1),      dim3(64),  0, stream, bfc, ws, out);
    hipLaunchKernelGGL(k_main,    dim3(1024),   dim3(256), 0, stream, x, w1, b1, ws, out);
}

// Round 3
// 45.389 us; speedup vs baseline: 1.5708x; 1.5708x over previous
//
#include <hip/hip_runtime.h>

#define Hdim   128
#define Anodes 512
#define Bbatch 64
#define Eedges 16384
#define AMASK  (Anodes - 1)

// ws float offsets
#define WS_CNT 0
#define WS_C   512
#define WS_S   1024
#define WS_U   (1024 + 65536)
#define WS_W1T (1024 + 65536 + 65536)   // bf16[128][128] = 16384 shorts = 8192 floats
#define WS_ZEND WS_W1T

typedef __attribute__((ext_vector_type(8))) short short8;
typedef __attribute__((ext_vector_type(4))) float f32x4;

__device__ __forceinline__ short f2bf(float f) {
    union { float f; unsigned u; } v; v.f = f;
    unsigned r = v.u + 0x7FFFu + ((v.u >> 16) & 1u);
    return (short)(r >> 16);
}

__global__ void k_init(float* ws) {
    int i = blockIdx.x * blockDim.x + threadIdx.x;
    for (; i < WS_ZEND; i += gridDim.x * blockDim.x) ws[i] = 0.f;
}

__global__ void k_cnt(const int* __restrict__ ei, float* __restrict__ ws) {
    int t = blockIdx.x * blockDim.x + threadIdx.x;
    if (t < Eedges) {
        int dst = ei[Eedges + t] & AMASK;
        atomicAdd(ws + WS_CNT + dst, 1.0f);
    }
}

// w1T_bf16[n][k] = bf16(w1[k][n]) into ws, via LDS tile transpose
__global__ void k_w1t(const float* __restrict__ w1, float* __restrict__ ws) {
    __shared__ float t[32][129];
    short* o = (short*)(ws + WS_W1T);
    const int k0 = blockIdx.x * 32;
    for (int i = threadIdx.x; i < 32 * 128; i += 256) {
        int r = i >> 7, c = i & 127;
        t[r][c] = w1[(k0 + r) * Hdim + c];
    }
    __syncthreads();
    const int n  = threadIdx.x >> 1;
    const int j0 = (threadIdx.x & 1) * 16;
    short tmp[16];
    #pragma unroll
    for (int j = 0; j < 16; ++j) tmp[j] = f2bf(t[j0 + j][n]);
    short8* dst = (short8*)(o + n * Hdim + k0 + j0);
    dst[0] = *(short8*)(tmp);
    dst[1] = *(short8*)(tmp + 8);
}

// Block a: W[a,h] = wfc[a*H+h]/max(cnt,1);  S[a,k] = sum_h w2[k*H+h]*W[a,h]
// Also accumulates C = sum_{a:cnt>0} sum_h b2[h]*wfc[a*H+h]
__global__ void k_S(const float* __restrict__ w2, const float* __restrict__ wfc,
                    const float* __restrict__ b2, float* __restrict__ ws) {
    __shared__ float Wrow[Hdim];
    __shared__ float red[2];
    const int a = blockIdx.x;
    const int h = threadIdx.x;
    const float c   = ws[WS_CNT + a];
    const float inv = 1.0f / fmaxf(c, 1.0f);
    const float wf  = wfc[a * Hdim + h];
    Wrow[h] = wf * inv;
    float cb = (c > 0.f) ? b2[h] * wf : 0.f;
    for (int off = 32; off; off >>= 1) cb += __shfl_down(cb, off, 64);
    if ((h & 63) == 0) red[h >> 6] = cb;
    __syncthreads();
    if (h == 0 && (red[0] + red[1]) != 0.f) atomicAdd(ws + WS_C, red[0] + red[1]);
    float s = 0.f;
    #pragma unroll 8
    for (int hh = 0; hh < Hdim; ++hh) s += w2[h * Hdim + hh] * Wrow[hh];
    ws[WS_S + a * Hdim + h] = s;
}

// U[src,:] += S[dst,:] over all edges
__global__ void k_U(const int* __restrict__ ei, float* __restrict__ ws) {
    int idx = blockIdx.x * blockDim.x + threadIdx.x;
    const int total = Eedges * Hdim;
    for (; idx < total; idx += gridDim.x * blockDim.x) {
        int e = idx >> 7, k = idx & (Hdim - 1);
        int src = ei[e] & AMASK, dst = ei[Eedges + e] & AMASK;
        atomicAdd(ws + WS_U + src * Hdim + k, ws[WS_S + dst * Hdim + k]);
    }
}

__global__ void k_outinit(const float* __restrict__ bfc, const float* __restrict__ ws,
                          float* __restrict__ out) {
    int t = threadIdx.x;
    if (t < Bbatch) out[t] = bfc[0] + ws[WS_C];
}

// MFMA: per block 64 rows; out[b] += sum_rows relu(x_row @ w1 + b1) . U[a,:]
__global__ __launch_bounds__(256)
void k_main(const float* __restrict__ x, const float* __restrict__ b1,
            const float* __restrict__ ws, float* __restrict__ out) {
    __shared__ short w1s[Hdim * Hdim];   // swizzled bf16 [n][k], 32 KB
    __shared__ float red[4];

    const int tid  = threadIdx.x;
    const int row0 = blockIdx.x * 64;
    const int b    = blockIdx.x >> 3;          // row0 / 512
    const int a0   = (blockIdx.x & 7) * 64;    // row0 % 512

    // stage w1T (global, linear bf16 [n][k]) -> LDS with XOR swizzle
    {
        const short8* gsrc = (const short8*)(ws + WS_W1T);
        for (int i = tid; i < 2048; i += 256) {      // 16384 shorts / 8
            short8 v = gsrc[i];
            int n = i >> 4;                           // 16 chunks per n-row
            int byte = (i * 16) ^ ((n & 7) << 4);
            *(short8*)((char*)w1s + byte) = v;
        }
    }
    __syncthreads();

    const int w = tid >> 6;       // wave 0..3 -> rows w*16..w*16+15
    const int l = tid & 63;
    const int c = l & 15;         // A: row-in-tile ; B/D: col-in-tile
    const int g = l >> 4;         // k-group

    const float* xrow = x + (size_t)(row0 + w * 16 + c) * Hdim;

    f32x4 acc[8];
    #pragma unroll
    for (int n = 0; n < 8; ++n) acc[n] = (f32x4){0.f, 0.f, 0.f, 0.f};

    #pragma unroll
    for (int ks = 0; ks < 4; ++ks) {
        const int k0 = ks * 32;
        // A frag: 8 contiguous f32 at xrow[k0 + 8g] -> bf16 (RNE)
        float4 a_lo = *(const float4*)(xrow + k0 + 8 * g);
        float4 a_hi = *(const float4*)(xrow + k0 + 8 * g + 4);
        short8 a;
        a[0] = f2bf(a_lo.x); a[1] = f2bf(a_lo.y); a[2] = f2bf(a_lo.z); a[3] = f2bf(a_lo.w);
        a[4] = f2bf(a_hi.x); a[5] = f2bf(a_hi.y); a[6] = f2bf(a_hi.z); a[7] = f2bf(a_hi.w);
        #pragma unroll
        for (int n = 0; n < 8; ++n) {
            // B frag: lane l holds w1T[n*16+c][k0+8g .. +7], swizzled addr
            int byte = (((n * 16 + c) << 8) + ((k0 + 8 * g) << 1)) ^ ((c & 7) << 4);
            short8 bf = *(short8*)((char*)w1s + byte);
            acc[n] = __builtin_amdgcn_mfma_f32_16x16x32_bf16(a, bf, acc[n], 0, 0, 0);
        }
    }

    // epilogue: z = acc + b1[col]; relu; dot with U[a,:]
    float part = 0.f;
    const float* U = ws + WS_U;
    #pragma unroll
    for (int n = 0; n < 8; ++n) {
        const int colg = n * 16 + c;
        const float bv = b1[colg];
        #pragma unroll
        for (int r = 0; r < 4; ++r) {
            const int arow = a0 + w * 16 + g * 4 + r;   // D row = (l>>4)*4 + reg
            float z = acc[n][r] + bv;
            part += fmaxf(z, 0.f) * U[arow * Hdim + colg];
        }
    }
    #pragma unroll
    for (int off = 32; off; off >>= 1) part += __shfl_down(part, off, 64);
    if (l == 0) red[w] = part;
    __syncthreads();
    if (tid == 0) atomicAdd(out + b, red[0] + red[1] + red[2] + red[3]);
}

extern "C" void kernel_launch(void* const* d_in, const int* in_sizes, int n_in,
                              void* d_out, int out_size, void* d_ws, size_t ws_size,
                              hipStream_t stream) {
    const float* x   = (const float*)d_in[0];
    // d_in[1] = pos (unused)
    const int*   ei  = (const int*)d_in[2];
    const float* w1  = (const float*)d_in[3];
    const float* b1  = (const float*)d_in[4];
    const float* w2  = (const float*)d_in[5];
    const float* b2  = (const float*)d_in[6];
    const float* wfc = (const float*)d_in[7];
    const float* bfc = (const float*)d_in[8];
    float* out = (float*)d_out;
    float* ws  = (float*)d_ws;

    hipLaunchKernelGGL(k_init,    dim3(256),    dim3(256),  0, stream, ws);
    hipLaunchKernelGGL(k_w1t,     dim3(4),      dim3(256),  0, stream, w1, ws);
    hipLaunchKernelGGL(k_cnt,     dim3(64),     dim3(256),  0, stream, ei, ws);
    hipLaunchKernelGGL(k_S,       dim3(Anodes), dim3(Hdim), 0, stream, w2, wfc, b2, ws);
    hipLaunchKernelGGL(k_U,       dim3(2048),   dim3(256),  0, stream, ei, ws);
    hipLaunchKernelGGL(k_outinit, dim3(1),      dim3(64),   0, stream, bfc, ws, out);
    hipLaunchKernelGGL(k_main,    dim3(512),    dim3(256),  0, stream, x, b1, ws, out);
}